// Round 7
// baseline (161.177 us; speedup 1.0000x reference)
//
#include <hip/hip_runtime.h>

// Round 13: NO-LDS direct-dataflow kernel (the untested opposite extreme).
// Evidence through R12: fused kernel stuck at 40-46us across staged variants,
// insensitive to memory level (warm L3 == cold HBM), wave count, ILP,
// occupancy, and strided-transaction count. ~10us VALU issue + ~10us memory
// floor vs 42.8us measured => ~30us unhidden stall. The single structural
// constant in all prior variants: stage -> __syncthreads+vmcnt(0) drain ->
// LDS-dependent compute. This round removes LDS and barriers entirely:
// each thread loads its own quad's data directly (L3-resident inputs,
// lane=consecutive-j so each load9 spans a contiguous ~2.3KB window),
// computes 3 edges, wave-reduces, one partial per block.
//
// Energy collapse (verified absmax==0 rounds 1-12):
//   sum_pq coeff[p][q](Dp.Dq) = 3(|u|^2+|w|^2+u.w) + (|a|^2+|b|^2+a.b), H=1.
// Adjacency (verified): quad q=(i,j), f1=tri1=i*m+j, tri2=Q+i*m+j.
//   diag : f2=tri2(i,j):   u=t1r2-t2r2, w=t1r1-t2r0; n1=N[v01], n2=N[v10]
//   horiz: f2=tri2(i-1,j): u=t1r0-t2r0, w=t1r2-t2r1; n1=N[v00], n2=N[v01]
//   vert : f2=tri2(i,j-1): u=t1r0-t2r2, w=t1r1-t2r1; n1=N[v00], n2=N[v10]
// Vertex normals = normal_of(tp[vertex_id]) (reference indexes face normals
// by VERTEX id; verified rounds 1-12).
// Clamp audit (all clamped/garbage values feed only masked terms):
//   act=(i<m&&j<m) masks the whole quad; ic=min(i,m-1), jc=min(j,m-1).
//   fh row clamp (ic-1<0) -> horiz masked by i>0. fv col clamp (jc-1<0) ->
//   vert masked by j>0. pup row clamp -> only used i>0. plf at jc=0 reads
//   row ic col n-1 (in-bounds garbage) -> used only j>0. All vertex-id and
//   face indices stay within allocations by construction (max checked:
//   (ic+1)*n+jc <= m*n+m-1 < n^2 <= F; faces < F; verts < V).

struct __attribute__((aligned(4))) F4s { float a, b, c, d; };
struct F3 { float x, y, z; };
struct R9 { float v[9]; };

__device__ __forceinline__ R9 load9(const float* __restrict__ p) {
    R9 r;
    F4s u0 = *(const F4s*)p;
    F4s u1 = *(const F4s*)(p + 4);
    r.v[0] = u0.a; r.v[1] = u0.b; r.v[2] = u0.c; r.v[3] = u0.d;
    r.v[4] = u1.a; r.v[5] = u1.b; r.v[6] = u1.c; r.v[7] = u1.d;
    r.v[8] = p[8];
    return r;
}

__device__ __forceinline__ F3 loadv3(const float* __restrict__ p) {
    F3 r; r.x = p[0]; r.y = p[1]; r.z = p[2]; return r;
}

__device__ __forceinline__ int imin(int a, int b) { return a < b ? a : b; }
__device__ __forceinline__ int imax(int a, int b) { return a > b ? a : b; }

__device__ __forceinline__ F3 normal_of(const R9& r) {
    float e1x = r.v[0] - r.v[3], e1y = r.v[1] - r.v[4], e1z = r.v[2] - r.v[5];
    float e2x = r.v[0] - r.v[6], e2y = r.v[1] - r.v[7], e2z = r.v[2] - r.v[8];
    float nx = e1y * e2z - e1z * e2y;
    float ny = e1z * e2x - e1x * e2z;
    float nz = e1x * e2y - e1y * e2x;
    float inv = 1.0f / sqrtf(nx * nx + ny * ny + nz * nz);
    F3 o; o.x = nx * inv; o.y = ny * inv; o.z = nz * inv; return o;
}

__device__ __forceinline__ float tri_area(const F3& p, const F3& q, const F3& r) {
    float ax = q.x - p.x, ay = q.y - p.y, az = q.z - p.z;
    float bx = r.x - p.x, by = r.y - p.y, bz = r.z - p.z;
    float cx = ay * bz - az * by, cy = az * bx - ax * bz, cz = ax * by - ay * bx;
    return 0.5f * sqrtf(cx * cx + cy * cy + cz * cz);
}

__device__ __forceinline__ float edge_ew(const float* u1, const float* u2,
                                         const float* w1, const float* w2,
                                         const float* rA, const float* rB,
                                         const F3& n1, const F3& n2,
                                         const F3& pa, const F3& pb,
                                         float asum) {
    float ux = u1[0] - u2[0], uy = u1[1] - u2[1], uz = u1[2] - u2[2];
    float wx = w1[0] - w2[0], wy = w1[1] - w2[1], wz = w1[2] - w2[2];

    float d0 = rA[0] - rB[0], d1 = rA[1] - rB[1], d2 = rA[2] - rB[2];
    float d3 = rA[3] - rB[3], d4 = rA[4] - rB[4], d5 = rA[5] - rB[5];
    float d6 = rA[6] - rB[6], d7 = rA[7] - rB[7], d8 = rA[8] - rB[8];

    float ax = n1.x * d0 + n1.y * d3 + n1.z * d6;
    float ay = n1.x * d1 + n1.y * d4 + n1.z * d7;
    float az = n1.x * d2 + n1.y * d5 + n1.z * d8;
    float bx = n2.x * d0 + n2.y * d3 + n2.z * d6;
    float by = n2.x * d1 + n2.y * d4 + n2.z * d7;
    float bz = n2.x * d2 + n2.y * d5 + n2.z * d8;

    float uu = ux * ux + uy * uy + uz * uz;
    float ww = wx * wx + wy * wy + wz * wz;
    float uw = ux * wx + uy * wy + uz * wz;
    float aa = ax * ax + ay * ay + az * az;
    float bb = bx * bx + by * by + bz * bz;
    float ab = ax * bx + ay * by + az * bz;
    float energy = (3.0f * (uu + ww + uw) + (aa + bb + ab)) * (1.0f / 9.0f);

    float dx = pa.x - pb.x, dy = pa.y - pb.y, dz = pa.z - pb.z;
    return energy * (dx * dx + dy * dy + dz * dz) / asum;
}

__global__ __launch_bounds__(256) void fused_kernel(
        const float* __restrict__ tp,    // (2Q,3,3)
        const float* __restrict__ rot,   // (2Q,3,3)
        const float* __restrict__ verts, // (n*n,3)
        double* __restrict__ partials,
        int n) {
    const int m = n - 1;
    const int Q = m * m;
    const int tid = threadIdx.x;
    const int lane = tid & 63;
    const int wv = tid >> 6;                 // 0..3: wave = one quad row
    const int i = blockIdx.y * 4 + wv;
    const int j = blockIdx.x * 64 + lane;    // consecutive j within wave
    const bool act = (i < m) && (j < m);

    const int ic = imin(i, m - 1);
    const int jc = imin(j, m - 1);

    // ---- face indices ----
    const int f1 = ic * m + jc;
    const int fd = Q + f1;                           // tri2(i,j)
    const int fh = Q + imax(ic - 1, 0) * m + jc;     // tri2(i-1,j), masked i>0
    const int fv = Q + ic * m + imax(jc - 1, 0);     // tri2(i,j-1), masked j>0

    // ---- direct loads (compiler schedules; fine-grained vmcnt) ----
    R9 t1  = load9(tp  + (size_t)9 * f1);
    R9 r1  = load9(rot + (size_t)9 * f1);
    R9 t2  = load9(tp  + (size_t)9 * fd);
    R9 r2  = load9(rot + (size_t)9 * fd);
    R9 thh = load9(tp  + (size_t)9 * fh);
    R9 rhh = load9(rot + (size_t)9 * fh);
    R9 tvv = load9(tp  + (size_t)9 * fv);
    R9 rvv = load9(rot + (size_t)9 * fv);

    // ---- verts (6 x vec3) ----
    const int v00 = ic * n + jc;
    F3 p00 = loadv3(verts + (size_t)3 * v00);
    F3 p01 = loadv3(verts + (size_t)3 * (v00 + 1));
    F3 p10 = loadv3(verts + (size_t)3 * (v00 + n));
    F3 p11 = loadv3(verts + (size_t)3 * (v00 + n + 1));
    F3 pup = loadv3(verts + (size_t)3 * (imax(ic - 1, 0) * n + jc + 1)); // masked i>0
    F3 plf = loadv3(verts + (size_t)3 * (v00 + n - 1)); // jc=0 -> in-bounds garbage, masked j>0

    // ---- vertex normals (reference: face-normal array indexed by vertex id) ----
    F3 nA = normal_of(load9(tp + (size_t)9 * (size_t)(ic * n + jc)));
    F3 nB = normal_of(load9(tp + (size_t)9 * (size_t)(ic * n + jc + 1)));
    F3 nC = normal_of(load9(tp + (size_t)9 * (size_t)((ic + 1) * n + jc)));

    // ---- areas ----
    float a1   = tri_area(p00, p10, p01);
    float a2c  = tri_area(p10, p11, p01);
    float a2up = tri_area(p00, p01, pup);
    float a2lf = tri_area(plf, p10, p00);

    // ---- three edges ----
    float sum = edge_ew(t1.v + 6, t2.v + 6, t1.v + 3, t2.v + 0, r1.v, r2.v,
                        nB, nC, p01, p10, a1 + a2c);
    float eh = edge_ew(t1.v + 0, thh.v + 0, t1.v + 6, thh.v + 3, r1.v, rhh.v,
                       nA, nB, p00, p01, a1 + a2up);
    float ev = edge_ew(t1.v + 0, tvv.v + 6, t1.v + 3, tvv.v + 3, r1.v, rvv.v,
                       nA, nC, p00, p10, a1 + a2lf);
    sum += (i > 0 ? eh : 0.0f);
    sum += (j > 0 ? ev : 0.0f);

    double term = act ? (double)sum : 0.0;

    // ---- wave reduce + cross-wave LDS-free combine via small smem ----
    __shared__ double sred[4];
#pragma unroll
    for (int off = 32; off > 0; off >>= 1) term += __shfl_down(term, off, 64);
    if (lane == 0) sred[wv] = term;
    __syncthreads();
    if (tid == 0)
        partials[blockIdx.y * gridDim.x + blockIdx.x] =
            sred[0] + sred[1] + sred[2] + sred[3];
}

__global__ __launch_bounds__(256) void finalize_kernel(
        const double* __restrict__ partials, int P, float* __restrict__ out) {
    double s = 0.0;
    for (int i = threadIdx.x; i < P; i += 256) s += partials[i];
#pragma unroll
    for (int off = 32; off > 0; off >>= 1) s += __shfl_down(s, off, 64);
    __shared__ double sred[4];
    int lane = threadIdx.x & 63, wid = threadIdx.x >> 6;
    if (lane == 0) sred[wid] = s;
    __syncthreads();
    if (threadIdx.x == 0) out[0] = (float)(sred[0] + sred[1] + sred[2] + sred[3]);
}

extern "C" void kernel_launch(void* const* d_in, const int* in_sizes, int n_in,
                              void* d_out, int out_size, void* d_ws, size_t ws_size,
                              hipStream_t stream) {
    const float* tp    = (const float*)d_in[0];
    const float* rot   = (const float*)d_in[1];
    const float* verts = (const float*)d_in[2];

    int V = in_sizes[2] / 3;
    int n = (int)(sqrtf((float)V) + 0.5f);
    int m = n - 1;

    double* partials = (double*)d_ws;
    float*  out      = (float*)d_out;

    dim3 grid((m + 63) / 64, (m + 3) / 4);
    int P = grid.x * grid.y;
    fused_kernel<<<grid, 256, 0, stream>>>(tp, rot, verts, partials, n);
    finalize_kernel<<<1, 256, 0, stream>>>(partials, P, out);
}

// Round 8
// 151.405 us; speedup vs baseline: 1.0645x; 1.0645x over previous
//
#include <hip/hip_runtime.h>

// Round 14: cross-tile software pipeline (T14 async-STAGE split), the one
// untested mechanism. Persistent blocks: 768 blocks x 3 tiles (8x32 quads),
// double-buffered LDS. Per iteration:
//   [A] issue DMA stage of tile t+1 into buf p^1          (fire-and-forget)
//   [B] issue VGPR loads (t1/r1, normals, vert-halo) of t+1
//   [C] compute tile t from buf p + regs(t)  <- hides A/B latency
//   [D] write-late: normal_of/halo ds_writes into buf p^1
//       (compiler's vmcnt wait for B here forces A complete too - older)
//   [E] __syncthreads  (outstanding==0 by construction: drains nothing)
// No manual vmcnt counting needed; order pinned with sched_barrier(0).
//
// LDS per buffer: faces 2x9x300 fl (33 faces/row, merged left halo), verts
// 10x100 fl, normals 9x99 fl, vert-halo 10x4 fl = 29.3KB; x2 = 58.7KB ->
// 2 blocks/CU. Tile regs double-buffered in VGPRs, statically indexed via
// full unroll (rule #20).
//
// Face rows: faces (Q + gi*m + j0-1 .. +31), gi=min(i0-1+r,m-1) (can be -1:
// base >= Q-m-1 >= 0, R10-verified). Quad col c reads face at float 9*(c+1);
// tv/rv at 9*c (merged halo, no branch). Verts left col via scalar sVh
// (merge unsafe at vr=0 & j0=0). Bank audit: FST=300==12 mod 32, reads at
// 9l (9 coprime 32) -> permutation per half-wave, 2-way max (free, m136);
// VST=100==4, NST=99==3 with 3l likewise.
//
// Energy collapse (verified absmax==0 rounds 1-13):
//   sum_pq coeff[p][q](Dp.Dq) = 3(|u|^2+|w|^2+u.w) + (|a|^2+|b|^2+a.b), H=1.
// Adjacency (verified): quad q=(i,j), f1=tri1=i*m+j, tri2=Q+i*m+j.
//   diag : f2=tri2(i,j):   u=t1r2-t2r2, w=t1r1-t2r0; n1=N[v01], n2=N[v10]
//   horiz: f2=tri2(i-1,j): u=t1r0-t2r0, w=t1r2-t2r1; n1=N[v00], n2=N[v01]
//   vert : f2=tri2(i,j-1): u=t1r0-t2r2, w=t1r1-t2r1; n1=N[v00], n2=N[v10]
// Clamp-garbage audit: identical consumers to R8/R10 (all masked by
// i<m&&j<m, i>0, j>0); face right-edge clamp floats feed only pad/j=m slots.

#define FST 300      // face LDS row stride (fl): 33 faces*9=297 + 3 pad; 75 ch
#define F_SLOTS 675  // 9 rows * 75 chunks, per array
#define VST 100      // vert row stride: 33*3=99 + 1 pad; 25 chunks
#define V_SLOTS 250  // 10 rows * 25 chunks
#define NST 99       // normals row stride (33*3)
#define NCNT 297     // 9 rows * 33
#define TPB 3        // tiles per block

struct __attribute__((aligned(4))) F4s { float a, b, c, d; };
struct F3 { float x, y, z; };
struct R9 { float v[9]; };
struct TileRegs { R9 t1, r1, nraw0, nraw1; float hval; };

__device__ __forceinline__ R9 load9(const float* __restrict__ p) {
    R9 r;
    F4s u0 = *(const F4s*)p;
    F4s u1 = *(const F4s*)(p + 4);
    r.v[0] = u0.a; r.v[1] = u0.b; r.v[2] = u0.c; r.v[3] = u0.d;
    r.v[4] = u1.a; r.v[5] = u1.b; r.v[6] = u1.c; r.v[7] = u1.d;
    r.v[8] = p[8];
    return r;
}

__device__ __forceinline__ int imin(int a, int b) { return a < b ? a : b; }
__device__ __forceinline__ int imax(int a, int b) { return a > b ? a : b; }

__device__ __forceinline__ void gload_lds16(const float* gp, float* lp) {
    __builtin_amdgcn_global_load_lds(
        (const __attribute__((address_space(1))) void*)gp,
        (__attribute__((address_space(3))) void*)lp, 16, 0, 0);
}

__device__ __forceinline__ F3 normal_of(const R9& r) {
    float e1x = r.v[0] - r.v[3], e1y = r.v[1] - r.v[4], e1z = r.v[2] - r.v[5];
    float e2x = r.v[0] - r.v[6], e2y = r.v[1] - r.v[7], e2z = r.v[2] - r.v[8];
    float nx = e1y * e2z - e1z * e2y;
    float ny = e1z * e2x - e1x * e2z;
    float nz = e1x * e2y - e1y * e2x;
    float inv = 1.0f / sqrtf(nx * nx + ny * ny + nz * nz);
    F3 o; o.x = nx * inv; o.y = ny * inv; o.z = nz * inv; return o;
}

__device__ __forceinline__ float tri_area_p(const float* p, const float* q,
                                            const float* r) {
    float ax = q[0] - p[0], ay = q[1] - p[1], az = q[2] - p[2];
    float bx = r[0] - p[0], by = r[1] - p[1], bz = r[2] - p[2];
    float cx = ay * bz - az * by, cy = az * bx - ax * bz, cz = ax * by - ay * bx;
    return 0.5f * sqrtf(cx * cx + cy * cy + cz * cz);
}

__device__ __forceinline__ float edge_ew(const float* u1, const float* u2,
                                         const float* w1, const float* w2,
                                         const float* rA, const float* rB,
                                         const F3& n1, const F3& n2,
                                         const float* pa, const float* pb,
                                         float asum) {
    float ux = u1[0] - u2[0], uy = u1[1] - u2[1], uz = u1[2] - u2[2];
    float wx = w1[0] - w2[0], wy = w1[1] - w2[1], wz = w1[2] - w2[2];

    float d0 = rA[0] - rB[0], d1 = rA[1] - rB[1], d2 = rA[2] - rB[2];
    float d3 = rA[3] - rB[3], d4 = rA[4] - rB[4], d5 = rA[5] - rB[5];
    float d6 = rA[6] - rB[6], d7 = rA[7] - rB[7], d8 = rA[8] - rB[8];

    float ax = n1.x * d0 + n1.y * d3 + n1.z * d6;
    float ay = n1.x * d1 + n1.y * d4 + n1.z * d7;
    float az = n1.x * d2 + n1.y * d5 + n1.z * d8;
    float bx = n2.x * d0 + n2.y * d3 + n2.z * d6;
    float by = n2.x * d1 + n2.y * d4 + n2.z * d7;
    float bz = n2.x * d2 + n2.y * d5 + n2.z * d8;

    float uu = ux * ux + uy * uy + uz * uz;
    float ww = wx * wx + wy * wy + wz * wz;
    float uw = ux * wx + uy * wy + uz * wz;
    float aa = ax * ax + ay * ay + az * az;
    float bb = bx * bx + by * by + bz * bz;
    float ab = ax * bx + ay * by + az * bz;
    float energy = (3.0f * (uu + ww + uw) + (aa + bb + ab)) * (1.0f / 9.0f);

    float dx = pa[0] - pb[0], dy = pa[1] - pb[1], dz = pa[2] - pb[2];
    return energy * (dx * dx + dy * dy + dz * dz) / asum;
}

__global__ __launch_bounds__(256) void fused_kernel(
        const float* __restrict__ tp,    // (2Q,3,3)
        const float* __restrict__ rot,   // (2Q,3,3)
        const float* __restrict__ verts, // (n*n,3)
        double* __restrict__ partials,
        int n) {
    const int m = n - 1;
    const int Q = m * m;
    const int F = 2 * Q;
    const int V = n * n;
    const int tid = threadIdx.x;
    const int wv = tid >> 6;
    const int lane = tid & 63;
    const int w = tid >> 5;          // quad row in tile, 0..7
    const int l = tid & 31;          // quad col in tile, 0..31

    const int nTj = (m + 31) / 32;
    const int nTi = (m + 7) / 8;
    const int nT = nTi * nTj;

    __shared__ __attribute__((aligned(16))) float sT2[2][9 * FST];
    __shared__ __attribute__((aligned(16))) float sR2[2][9 * FST];
    __shared__ __attribute__((aligned(16))) float sV[2][10 * VST];
    __shared__ float sN[2][9 * NST];
    __shared__ float sVh[2][10 * 4];
    __shared__ double sred[4];

    auto stage_dma = [&](int p, int i0, int j0) {
#pragma unroll
        for (int it = 0; it < 7; ++it) {
            int ws = it * 4 + wv;              // wave-uniform slot id
            if (ws < 22) {
                int a = ws >= 11;
                int wl = a ? ws - 11 : ws;
                int ch = wl * 64 + lane;       // lane-linear
                if (ch < F_SLOTS) {
                    int r = ch / 75, c = ch - 75 * r;
                    int gi = imin(i0 - 1 + r, m - 1);          // can be -1
                    int g = 9 * (Q + gi * m + (j0 - 1)) + 4 * c;  // >= 0
                    g = imin(g, 9 * F - 4);
                    gload_lds16((a ? rot : tp) + g,
                                (a ? sR2[p] : sT2[p]) + ch * 4);
                }
            } else if (ws < 26) {
                int ch = (ws - 22) * 64 + lane;
                if (ch < V_SLOTS) {
                    int r = ch / 25, c = ch - 25 * r;
                    int vr = imax(imin(i0 - 1 + r, n - 1), 0);
                    int g = 3 * (vr * n + j0) + 4 * c;
                    g = imin(g, 3 * V - 4);
                    gload_lds16(verts + g, sV[p] + ch * 4);
                }
            }
        }
    };

    auto stage_regs = [&](TileRegs& tr, int i0, int j0) {
        int i = i0 + w, j = j0 + l;
        int f1 = imin(i, m - 1) * m + imin(j, m - 1);
        tr.t1 = load9(tp  + (size_t)9 * f1);
        tr.r1 = load9(rot + (size_t)9 * f1);
        {
            int s = tid;                       // < 256 < NCNT always
            int r = s / 33, c = s - 33 * r;
            int gi = imin(i0 + r, n - 1), gj = imin(j0 + c, n - 1);
            tr.nraw0 = load9(tp + (size_t)9 * (size_t)(gi * n + gj));
        }
        {
            int s = tid + 256;
            int sc = (s < NCNT) ? s : 0;
            int r = sc / 33, c = sc - 33 * r;
            int gi = imin(i0 + r, n - 1), gj = imin(j0 + c, n - 1);
            tr.nraw1 = load9(tp + (size_t)9 * (size_t)(gi * n + gj));
        }
        tr.hval = 0.0f;
        if (tid < 30) {
            int r = tid / 3, k = tid - 3 * r;
            int vr = imax(imin(i0 - 1 + r, n - 1), 0);
            tr.hval = verts[imax(3 * (vr * n + (j0 - 1)) + k, 0)];
        }
    };

    auto write_regs = [&](int p, TileRegs& tr) {
        {
            int s = tid;
            int r = s / 33, c = s - 33 * r;
            F3 nm = normal_of(tr.nraw0);
            int o = r * NST + 3 * c;
            sN[p][o] = nm.x; sN[p][o + 1] = nm.y; sN[p][o + 2] = nm.z;
        }
        if (tid + 256 < NCNT) {
            int s = tid + 256;
            int r = s / 33, c = s - 33 * r;
            F3 nm = normal_of(tr.nraw1);
            int o = r * NST + 3 * c;
            sN[p][o] = nm.x; sN[p][o + 1] = nm.y; sN[p][o + 2] = nm.z;
        }
        if (tid < 30) {
            int r = tid / 3, k = tid - 3 * r;
            sVh[p][r * 4 + k] = tr.hval;
        }
    };

    auto compute_tile = [&](int p, int i0, int j0, const TileRegs& tr) -> double {
        int i = i0 + w, j = j0 + l;
        if (i >= m || j >= m) return 0.0;
        const float* fT = sT2[p];
        const float* fR = sR2[p];
        const float* t2c = fT + (w + 1) * FST + 9 * (l + 1);
        const float* r2c = fR + (w + 1) * FST + 9 * (l + 1);
        const float* th  = fT + w * FST + 9 * (l + 1);
        const float* rh  = fR + w * FST + 9 * (l + 1);
        const float* tv  = fT + (w + 1) * FST + 9 * l;   // merged halo
        const float* rv  = fR + (w + 1) * FST + 9 * l;

        const float* vb = sV[p];
        const float* p00 = vb + (w + 1) * VST + 3 * l;
        const float* p01 = p00 + 3;
        const float* p10 = vb + (w + 2) * VST + 3 * l;
        const float* p11 = p10 + 3;
        const float* pup = vb + w * VST + 3 * (l + 1);
        const float* plf = l ? vb + (w + 2) * VST + 3 * (l - 1)
                             : sVh[p] + (w + 2) * 4;

        const float* na = sN[p] + w * NST + 3 * l;
        const float* nb = na + 3;
        const float* nc = sN[p] + (w + 1) * NST + 3 * l;
        F3 nA = { na[0], na[1], na[2] };
        F3 nB = { nb[0], nb[1], nb[2] };
        F3 nC = { nc[0], nc[1], nc[2] };

        float a1   = tri_area_p(p00, p10, p01);
        float a2c  = tri_area_p(p10, p11, p01);
        float a2up = tri_area_p(p00, p01, pup);
        float a2lf = tri_area_p(plf, p10, p00);

        float sum = edge_ew(tr.t1.v + 6, t2c + 6, tr.t1.v + 3, t2c + 0,
                            tr.r1.v, r2c, nB, nC, p01, p10, a1 + a2c);
        float eh = edge_ew(tr.t1.v + 0, th + 0, tr.t1.v + 6, th + 3,
                           tr.r1.v, rh, nA, nB, p00, p01, a1 + a2up);
        float ev = edge_ew(tr.t1.v + 0, tv + 6, tr.t1.v + 3, tv + 3,
                           tr.r1.v, rv, nA, nC, p00, p10, a1 + a2lf);
        sum += (i > 0 ? eh : 0.0f);
        sum += (j > 0 ? ev : 0.0f);
        return (double)sum;
    };

    const int tau0 = blockIdx.x * TPB;
    TileRegs regA, regB;   // static double-buffer (full unroll below)

    // ---- prologue: fully stage tile tau0 into buffer 0 / regA ----
    {
        int tau = tau0;
        if (tau < nT) {
            int ti = tau / nTj, tj = tau - ti * nTj;
            int i0 = ti * 8, j0 = tj * 32;
            stage_dma(0, i0, j0);
            stage_regs(regA, i0, j0);
            write_regs(0, regA);   // vmcnt wait here also completes the DMA
        }
    }
    __syncthreads();

    double wsum = 0.0;
#pragma unroll
    for (int tt = 0; tt < TPB; ++tt) {
        const int p = tt & 1;
        const int tau = tau0 + tt;
        const bool live = tau < nT;
        int ti = tau / nTj, tj = tau - ti * nTj;
        const int i0 = ti * 8, j0 = tj * 32;

        const int taun = tau + 1;
        const bool liven = (tt < TPB - 1) && (taun < nT);
        int tin = taun / nTj, tjn = taun - tin * nTj;
        const int i0n = tin * 8, j0n = tjn * 32;

        // [A]+[B]: issue next tile's loads (DMA first, then VGPR loads)
        if (liven) {
            stage_dma(p ^ 1, i0n, j0n);
            if (tt & 1) stage_regs(regA, i0n, j0n);
            else        stage_regs(regB, i0n, j0n);
        }
        __builtin_amdgcn_sched_barrier(0);

        // [C]: compute current tile (hides A/B latency)
        if (live) wsum += compute_tile(p, i0, j0, (tt & 1) ? regB : regA);
        __builtin_amdgcn_sched_barrier(0);

        // [D]: write-late next tile's normals/halo (forces DMA complete too)
        if (liven) {
            if (tt & 1) write_regs(p ^ 1, regA);
            else        write_regs(p ^ 1, regB);
        }
        if (tt < TPB - 1) __syncthreads();   // outstanding==0: free drain
    }

    // ---- block reduction (once per block) ----
#pragma unroll
    for (int off = 32; off > 0; off >>= 1) wsum += __shfl_down(wsum, off, 64);
    if (lane == 0) sred[wv] = wsum;
    __syncthreads();
    if (tid == 0)
        partials[blockIdx.x] = sred[0] + sred[1] + sred[2] + sred[3];
}

__global__ __launch_bounds__(256) void finalize_kernel(
        const double* __restrict__ partials, int P, float* __restrict__ out) {
    double s = 0.0;
    for (int i = threadIdx.x; i < P; i += 256) s += partials[i];
#pragma unroll
    for (int off = 32; off > 0; off >>= 1) s += __shfl_down(s, off, 64);
    __shared__ double sred[4];
    int lane = threadIdx.x & 63, wid = threadIdx.x >> 6;
    if (lane == 0) sred[wid] = s;
    __syncthreads();
    if (threadIdx.x == 0) out[0] = (float)(sred[0] + sred[1] + sred[2] + sred[3]);
}

extern "C" void kernel_launch(void* const* d_in, const int* in_sizes, int n_in,
                              void* d_out, int out_size, void* d_ws, size_t ws_size,
                              hipStream_t stream) {
    const float* tp    = (const float*)d_in[0];
    const float* rot   = (const float*)d_in[1];
    const float* verts = (const float*)d_in[2];

    int V = in_sizes[2] / 3;
    int n = (int)(sqrtf((float)V) + 0.5f);
    int m = n - 1;

    double* partials = (double*)d_ws;
    float*  out      = (float*)d_out;

    int nTj = (m + 31) / 32, nTi = (m + 7) / 8;
    int nT = nTi * nTj;
    int nBlocks = (nT + TPB - 1) / TPB;

    fused_kernel<<<nBlocks, 256, 0, stream>>>(tp, rot, verts, partials, n);
    finalize_kernel<<<1, 256, 0, stream>>>(partials, nBlocks, out);
}